// Round 8
// baseline (361.540 us; speedup 1.0000x reference)
//
#include <hip/hip_runtime.h>
#include <stdint.h>
#include <math.h>

// ---------------------------------------------------------------------------
// MultiHeadAttention: B=4, S=2048, D=1024, H=16, dk=64
// Raw-reshape head split: head (b,h) = rows [b*2048+h*128, +128) of the
// projected [8192][1024] matrix, reinterpreted as [2048][64].
// R10 = R9 + GEMM BK=64 + attn micro-VALU cuts.
//   - gemm_bt: K-step 32->64. Halves the per-K barrier/vmcnt(0) drains (the
//     m97 structure's known ~20% stall), 32 MFMA per stage. LDS rows are now
//     128B (16-way conflict hazard) -> both-sides XOR swizzle: pre-swizzled
//     GLOBAL source col (seg^(row&7)) + linear gld_lds dest + swizzled
//     fragment read (same-convention A/B halves: k-permutation cancels).
//     LDS 32KB (not BK=128's 64KB occupancy cliff).
//   - attn: first QK^T MFMA per tile takes the persistent zero f32x16 as
//     C-in (kills 64 v_mov/tile); max tree via v_max3_f32 (31->20 ops/qg).
// Kept from R9: native v_exp_f32 softmax, 64 q-rows/wave, 2 blocks/CU
// L2-resident regime (R6: more blocks thrashes L2), 32x32x16 MFMA attn path,
// layout-proof P-through-LDS, pkrtz, defer-max, async gld_lds dbuf staging.
// ---------------------------------------------------------------------------

typedef __attribute__((ext_vector_type(8))) short short8;
typedef __attribute__((ext_vector_type(4))) float f32x4;
typedef __attribute__((ext_vector_type(16))) float f32x16;
typedef __attribute__((ext_vector_type(2))) unsigned int u32x2;
typedef __attribute__((ext_vector_type(4))) unsigned int u32x4;
typedef __attribute__((ext_vector_type(8))) _Float16 half8;

__device__ __forceinline__ unsigned short bf16rne(float f) {
  unsigned int u = __builtin_bit_cast(unsigned int, f);
  unsigned int r = u + 0x7FFFu + ((u >> 16) & 1u);
  return (unsigned short)(r >> 16);
}

// async global->LDS, 16B per lane. LDS dest must be wave-uniform base + lane*16.
__device__ __forceinline__ void gld_lds16(const void* g, void* l) {
  typedef __attribute__((address_space(3))) unsigned int lds_u32;
  typedef const __attribute__((address_space(1))) unsigned int glb_u32;
  __builtin_amdgcn_global_load_lds((glb_u32*)(uintptr_t)g,
                                   (lds_u32*)(unsigned int)(uintptr_t)l,
                                   16, 0, 0);
}

// pack two f32 -> one u32 of two f16 (RTZ, single v_cvt_pkrtz_f16_f32)
__device__ __forceinline__ unsigned pkrtz(float a, float b) {
  auto h = __builtin_amdgcn_cvt_pkrtz(a, b);  // __fp16 ext_vector_type(2)
  return __builtin_bit_cast(unsigned, h);
}

// bare v_exp_f32 (2^x); no -ffast-math in harness so exp2f() is OCML multi-op.
__device__ __forceinline__ float fexp2(float x) {
#if __has_builtin(__builtin_amdgcn_exp2f)
  return __builtin_amdgcn_exp2f(x);
#else
  float r;
  asm("v_exp_f32 %0, %1" : "=v"(r) : "v"(x));
  return r;
#endif
}

// single-instruction 3-input max
__device__ __forceinline__ float max3f(float a, float b, float c) {
  float r;
  asm("v_max3_f32 %0, %1, %2, %3" : "=v"(r) : "v"(a), "v"(b), "v"(c));
  return r;
}

// ---------------------------------------------------------------------------
// fp32 -> bf16 convert for Q,K,V   (3 x 8192 x 1024)
// ---------------------------------------------------------------------------
__global__ void convert_x_kernel(const float* __restrict__ Q,
                                 const float* __restrict__ K,
                                 const float* __restrict__ V,
                                 unsigned short* __restrict__ Xb) {
  const int z = blockIdx.y;
  const float* src = (z == 0) ? Q : (z == 1) ? K : V;
  const size_t i0 = ((size_t)blockIdx.x * 256 + threadIdx.x) * 8;
  const f32x4 a = *(const f32x4*)(src + i0);
  const f32x4 c = *(const f32x4*)(src + i0 + 4);
  u32x4 o;
  o[0] = (unsigned)bf16rne(a[0]) | ((unsigned)bf16rne(a[1]) << 16);
  o[1] = (unsigned)bf16rne(a[2]) | ((unsigned)bf16rne(a[3]) << 16);
  o[2] = (unsigned)bf16rne(c[0]) | ((unsigned)bf16rne(c[1]) << 16);
  o[3] = (unsigned)bf16rne(c[2]) | ((unsigned)bf16rne(c[3]) << 16);
  *(u32x4*)(Xb + (size_t)z * 8388608 + i0) = o;
}

// ---------------------------------------------------------------------------
// W [K=1024][N=1024] fp32 -> Wt [N][K] bf16 (transposed so GEMMs are A*B^T)
// ---------------------------------------------------------------------------
__global__ void convert_w_kernel(const float* __restrict__ W0,
                                 const float* __restrict__ W1,
                                 const float* __restrict__ W2,
                                 const float* __restrict__ W3,
                                 unsigned short* __restrict__ Wt) {
  const int z = blockIdx.z;
  const float* W = (z == 0) ? W0 : (z == 1) ? W1 : (z == 2) ? W2 : W3;
  unsigned short* dst = Wt + (size_t)z * 1048576;
  __shared__ float tile[32][33];
  const int tx = threadIdx.x & 31, ty = threadIdx.x >> 5;
  const int k0 = blockIdx.x * 32, n0 = blockIdx.y * 32;
#pragma unroll
  for (int yy = 0; yy < 32; yy += 8)
    tile[ty + yy][tx] = W[(size_t)(k0 + ty + yy) * 1024 + n0 + tx];
  __syncthreads();
#pragma unroll
  for (int yy = 0; yy < 32; yy += 8)
    dst[(size_t)(n0 + ty + yy) * 1024 + k0 + tx] = bf16rne(tile[tx][ty + yy]);
}

// ---------------------------------------------------------------------------
// GEMM: C[z] = A[z][8192x1024] * Bt[z][1024x1024]^T.  BK=64, XOR-swizzled
// LDS (128B rows): global source col pre-swizzled seg^(row&7), linear
// gld_lds dest, fragment reads apply the same XOR -> residual 2-way
// conflict only (free). 32 MFMA per barrier-pair (was 16).
// ---------------------------------------------------------------------------
__global__ __launch_bounds__(256, 2) void gemm_bt_kernel(
    const unsigned short* __restrict__ A, const unsigned short* __restrict__ Bt,
    unsigned short* __restrict__ Cbf, float* __restrict__ Cf32, float scaleZ0) {
  constexpr int K = 1024, N = 1024;
  const int z = blockIdx.z;
  const unsigned short* Ab = A + (size_t)z * 8192 * 1024;
  const unsigned short* Bb = Bt + (size_t)z * 1024 * 1024;
  const int tid = threadIdx.x;
  const int lane = tid & 63;
  const int w = tid >> 6;
  const int l15 = lane & 15, quad = lane >> 4;
  const int rowBase = blockIdx.x * 128;
  const int colBase = blockIdx.y * 128;
  const int wrow = (w >> 1) * 64;
  const int wcol = (w & 1) * 64;
  __shared__ __align__(16) unsigned short As[128 * 64];  // 16 KB
  __shared__ __align__(16) unsigned short Bs[128 * 64];  // 16 KB

  const f32x4 z4 = {0.0f, 0.0f, 0.0f, 0.0f};
  f32x4 acc[4][4];
#pragma unroll
  for (int i = 0; i < 4; i++)
#pragma unroll
    for (int j = 0; j < 4; j++) acc[i][j] = z4;

  for (int k0 = 0; k0 < K; k0 += 64) {
    // stage 128x64 of A and B: 4 gld_lds each; slot = it*256+tid;
    // row = slot>>3, seg = slot&7; source col pre-swizzled (seg^(row&7)).
#pragma unroll
    for (int it = 0; it < 4; it++) {
      const int slot = it * 256 + tid;
      const int row = slot >> 3;
      const int sseg = (slot & 7) ^ (row & 7);
      gld_lds16(Ab + (size_t)(rowBase + row) * K + k0 + sseg * 8,
                (void*)(As + slot * 8));
      gld_lds16(Bb + (size_t)(colBase + row) * K + k0 + sseg * 8,
                (void*)(Bs + slot * 8));
    }
    __syncthreads();
    short8 af[4][2], bfr[4][2];
#pragma unroll
    for (int i = 0; i < 4; i++) {
      const int row = wrow + i * 16 + l15;
#pragma unroll
      for (int kk = 0; kk < 2; kk++)
        af[i][kk] =
            *(const short8*)(As + (row * 8 + ((kk * 4 + quad) ^ (row & 7))) * 8);
    }
#pragma unroll
    for (int j = 0; j < 4; j++) {
      const int row = wcol + j * 16 + l15;
#pragma unroll
      for (int kk = 0; kk < 2; kk++)
        bfr[j][kk] =
            *(const short8*)(Bs + (row * 8 + ((kk * 4 + quad) ^ (row & 7))) * 8);
    }
#pragma unroll
    for (int kk = 0; kk < 2; kk++)
#pragma unroll
      for (int i = 0; i < 4; i++)
#pragma unroll
        for (int j = 0; j < 4; j++)
          acc[i][j] = __builtin_amdgcn_mfma_f32_16x16x32_bf16(
              af[i][kk], bfr[j][kk], acc[i][j], 0, 0, 0);
    __syncthreads();
  }

  const float sc = (z == 0) ? scaleZ0 : 1.0f;
#pragma unroll
  for (int i = 0; i < 4; i++) {
#pragma unroll
    for (int j = 0; j < 4; j++) {
#pragma unroll
      for (int r = 0; r < 4; r++) {
        const int row = rowBase + wrow + i * 16 + quad * 4 + r;
        const int col = colBase + wcol + j * 16 + l15;
        const float v = acc[i][j][r] * sc;
        if (Cbf != nullptr) {
          Cbf[(size_t)z * 8192 * 1024 + (size_t)row * N + col] = bf16rne(v);
        } else {
          Cf32[(size_t)row * N + col] = v;
        }
      }
    }
  }
}

// ---------------------------------------------------------------------------
// V transpose: lin_v head (b,h) [2048][64] bf16 -> Vt[bh][64][2048] f16.
// ---------------------------------------------------------------------------
__global__ void vtrans_kernel(const unsigned short* __restrict__ linv,
                              unsigned short* __restrict__ Vt) {
  const int st = blockIdx.x, bh = blockIdx.y;
  const unsigned short* vp = linv + (size_t)bh * 131072;
  __shared__ unsigned short tile[64 * 136];
  const int tid = threadIdx.x;
#pragma unroll
  for (int it = 0; it < 4; it++) {
    const int idx = it * 256 + tid;        // 0..1023
    const int s = idx >> 3, d0 = (idx & 7) * 8;
    const u32x4 vv = *(const u32x4*)(vp + (size_t)(st * 128 + s) * 64 + d0);
#pragma unroll
    for (int m = 0; m < 4; m++) {
      const unsigned lo = vv[m] & 0xffffu, hi = vv[m] >> 16;
      const float f0 = __builtin_bit_cast(float, lo << 16);
      const float f1 = __builtin_bit_cast(float, hi << 16);
      const _Float16 h0 = (_Float16)f0, h1 = (_Float16)f1;
      tile[(d0 + 2 * m) * 136 + s] = __builtin_bit_cast(unsigned short, h0);
      tile[(d0 + 2 * m + 1) * 136 + s] = __builtin_bit_cast(unsigned short, h1);
    }
  }
  __syncthreads();
#pragma unroll
  for (int it = 0; it < 4; it++) {
    const int idx = it * 256 + tid;
    const int d = idx >> 4, s0 = (idx & 15) * 8;
    const u32x4 o = *(const u32x4*)(tile + d * 136 + s0);
    *(u32x4*)(Vt + (size_t)bh * 131072 + (size_t)d * 2048 + st * 128 + s0) = o;
  }
}

// ---------------------------------------------------------------------------
// Flash attention, 32x32 MFMA path, async-LDS double-buffered, 64 q/wave.
// Grid (bh=64, qt=8); block 256 = 4 waves; wave w owns q-rows
// [qt*256 + w*64, +64) as two q-groups qg=0,1 of 32; lane's q = qg*32+l31.
// LDS 48KB (2 resident blocks/CU -- L2-resident regime; DO NOT raise
// blocks/CU: R6 thrashed L2, fetch 45->198MB).
// Ks [2][64 key][64 dk] bf16 16KB + Vs [2][64 d][64 key] f16 16KB (both
// XOR-swizzled 16B segs, seg^(row&7)) + per-wave P tile [32 q][64 key] f16
// 4KB x4 = 16KB (reused across qg; same-wave LDS is in-order).
// S^T = mfma_32x32x16_bf16(K, Q): C col = q = l31, row = key =
// (r&3)+8*(r>>2)+4*(l>>5)  [HW-verified layout]. First MFMA of each tile
// uses the persistent zero f32x16 as C-in (no per-tile acc zeroing).
// K/V fragments read ONCE per tile, used by both q-groups.
// PV per 32-key group g: P packed (pkrtz) and ds_written at its true key
// index, read back as B-fragments with the SAME convention as the V
// A-fragments (unknown k-slot permutations cancel between PV operands).
// ---------------------------------------------------------------------------
__global__ __launch_bounds__(256, 2) void attn_kernel(
    const unsigned short* __restrict__ lin, const _Float16* __restrict__ Vt,
    unsigned short* __restrict__ ctxr) {
  const int bh = blockIdx.x;
  const int qt = blockIdx.y;
  const int b = bh >> 4, h = bh & 15;
  const int tid = threadIdx.x, lane = tid & 63, w = tid >> 6;
  const int l31 = lane & 31, hl = lane >> 5, x7 = l31 & 7;
  const size_t headOff = (size_t)(b * 2048 + h * 128) * 1024;
  const unsigned short* qp = lin + headOff;
  const unsigned short* kp = lin + 8388608 + headOff;
  const _Float16* vtp = Vt + (size_t)bh * 131072;

  __shared__ __align__(16) unsigned short smem[24576];  // 48 KB
  unsigned short(*Ks)[4096] = (unsigned short(*)[4096])smem;     // [2][4096]
  _Float16(*Vs)[4096] = (_Float16(*)[4096])(smem + 8192);        // [2][4096]
  _Float16* Pl = (_Float16*)(smem + 16384) + w * 2048;           // [32][64]

  // Staging geometry: waves 0,1 stage K (512 slots); waves 2,3 stage V.
  const int stageV = (w >= 2);
  const int wbase = (stageV ? (w - 2) : w) * 256 + lane;
  auto stage = [&](int bufn, int key0) {
#pragma unroll
    for (int i = 0; i < 4; i++) {
      const int slot = wbase + i * 64;
      const int row = slot >> 3;                 // key (K) or d (V)
      const int seg = (slot & 7) ^ (row & 7);    // un-swizzled segment
      if (!stageV) {
        gld_lds16(kp + (size_t)(key0 + row) * 64 + seg * 8,
                  (void*)(&Ks[bufn][slot * 8]));
      } else {
        gld_lds16(vtp + (size_t)row * 2048 + key0 + seg * 8,
                  (void*)(&Vs[bufn][slot * 8]));
      }
    }
  };

  // Q B-fragments (col = q = l31, k-window ks*16 + hl*8) for both q-groups.
  const int qrow0 = qt * 256 + w * 64;
  short8 bq[2][4];
#pragma unroll
  for (int qg = 0; qg < 2; qg++)
#pragma unroll
    for (int ks = 0; ks < 4; ks++)
      bq[qg][ks] = *(const short8*)(qp +
                                    (size_t)(qrow0 + qg * 32 + l31) * 64 +
                                    ks * 16 + hl * 8);

  f32x16 z16;
#pragma unroll
  for (int r = 0; r < 16; r++) z16[r] = 0.0f;
  f32x16 co[2][2] = {{z16, z16}, {z16, z16}};  // [qg][dt]
  float mrun[2] = {-INFINITY, -INFINITY};
  float lrun[2] = {0.0f, 0.0f};

  stage(0, 0);
  __syncthreads();

  for (int kt = 0; kt < 32; kt++) {
    const int cur = kt & 1;
    if (kt < 31) stage(cur ^ 1, (kt + 1) * 64);

    // ---- K fragments ONCE (8x ds_read_b128), shared by both q-groups.
    short8 kf[2][4];
#pragma unroll
    for (int g = 0; g < 2; g++)
#pragma unroll
      for (int ks = 0; ks < 4; ks++) {
        const int slot = (g * 32 + l31) * 8 + ((2 * ks + hl) ^ x7);
        kf[g][ks] = *(const short8*)(&Ks[cur][slot * 8]);
      }

    // ---- S^T: 16x mfma_32x32x16_bf16; ks=0 takes z16 as C-in (no zeroing).
    f32x16 sacc[2][2];  // [qg][g]
    __builtin_amdgcn_s_setprio(1);
#pragma unroll
    for (int qg = 0; qg < 2; qg++)
#pragma unroll
      for (int g = 0; g < 2; g++) {
        sacc[qg][g] = __builtin_amdgcn_mfma_f32_32x32x16_bf16(
            kf[g][0], bq[qg][0], z16, 0, 0, 0);
#pragma unroll
        for (int ks = 1; ks < 4; ks++)
          sacc[qg][g] = __builtin_amdgcn_mfma_f32_32x32x16_bf16(
              kf[g][ks], bq[qg][ks], sacc[qg][g], 0, 0, 0);
      }
    __builtin_amdgcn_s_setprio(0);

    // ---- V A-fragments ONCE (8x ds_read_b128), shared by both q-groups.
    half8 vf[2][2][2];  // [dt][g][s]
#pragma unroll
    for (int dt = 0; dt < 2; dt++)
#pragma unroll
      for (int g = 0; g < 2; g++)
#pragma unroll
        for (int s = 0; s < 2; s++) {
          const int slot = (dt * 32 + l31) * 8 + ((4 * g + 2 * s + hl) ^ x7);
          vf[dt][g][s] = *(const half8*)(&Vs[cur][slot * 8]);
        }

    // ---- per q-group: softmax + P pack/write/read + PV
#pragma unroll
    for (int qg = 0; qg < 2; qg++) {
      float pmax;
      {
        float tm[8];
#pragma unroll
        for (int r = 0; r < 8; r++)
          tm[r] = fmaxf(max3f(sacc[qg][0][r], sacc[qg][0][r + 8],
                              sacc[qg][1][r]),
                        sacc[qg][1][r + 8]);
        const float a0 = max3f(tm[0], tm[1], tm[2]);
        const float a1 = max3f(tm[3], tm[4], tm[5]);
        const float a2 = fmaxf(tm[6], tm[7]);
        pmax = max3f(a0, a1, a2);
      }
      pmax = fmaxf(pmax, __shfl_xor(pmax, 32, 64));
      if (!__all(pmax - mrun[qg] <= 8.0f)) {  // defer-max
        const float mnew = fmaxf(mrun[qg], pmax);
        const float a = fexp2(mrun[qg] - mnew);
        mrun[qg] = mnew;
        lrun[qg] *= a;
#pragma unroll
        for (int r = 0; r < 16; r++) {
          co[qg][0][r] *= a;
          co[qg][1][r] *= a;
        }
      }
      float ls0 = 0.0f, ls1 = 0.0f, ls2 = 0.0f, ls3 = 0.0f;
#pragma unroll
      for (int g = 0; g < 2; g++) {
#pragma unroll
        for (int r = 0; r < 16; r += 4) {
          const float p0 = fexp2(sacc[qg][g][r + 0] - mrun[qg]);
          const float p1 = fexp2(sacc[qg][g][r + 1] - mrun[qg]);
          const float p2 = fexp2(sacc[qg][g][r + 2] - mrun[qg]);
          const float p3 = fexp2(sacc[qg][g][r + 3] - mrun[qg]);
          sacc[qg][g][r + 0] = p0;
          sacc[qg][g][r + 1] = p1;
          sacc[qg][g][r + 2] = p2;
          sacc[qg][g][r + 3] = p3;
          ls0 += p0;
          ls1 += p1;
          ls2 += p2;
          ls3 += p3;
        }
      }
      lrun[qg] += (ls0 + ls1) + (ls2 + ls3);

      // P -> per-wave LDS tile at true key index (C-layout key_in_grp =
      // 8rg+4hl+t), then B-fragments with the V A-fragment convention;
      // g's MFMAs overlap g+1's pack. Pl reused across qg (in-order LDS).
#pragma unroll
      for (int g = 0; g < 2; g++) {
#pragma unroll
        for (int rg = 0; rg < 4; rg++) {
          u32x2 pw;
          pw[0] = pkrtz(sacc[qg][g][4 * rg + 0], sacc[qg][g][4 * rg + 1]);
          pw[1] = pkrtz(sacc[qg][g][4 * rg + 2], sacc[qg][g][4 * rg + 3]);
          *(u32x2*)(Pl + l31 * 64 + (((4 * g + rg) ^ x7) * 8) + hl * 4) = pw;
        }
        half8 pf[2];
#pragma unroll
        for (int s = 0; s < 2; s++)
          pf[s] =
              *(const half8*)(Pl + l31 * 64 + (((4 * g + 2 * s + hl) ^ x7) * 8));
        __builtin_amdgcn_s_setprio(1);
#pragma unroll
        for (int dt = 0; dt < 2; dt++)
#pragma unroll
          for (int s = 0; s < 2; s++)
            co[qg][dt] = __builtin_amdgcn_mfma_f32_32x32x16_f16(
                vf[dt][g][s], pf[s], co[qg][dt], 0, 0, 0);
        __builtin_amdgcn_s_setprio(0);
      }
    }
    __syncthreads();  // drains stage loads; separates buffer reuse
  }

  // ---- epilogue: normalize, transpose via LDS, coalesced b128 stores.
  unsigned short* Cw = smem + w * 4608;  // per-wave 64 rows x stride 72
#pragma unroll
  for (int qg = 0; qg < 2; qg++) {
    const float l = lrun[qg] + __shfl_xor(lrun[qg], 32, 64);
    const float inv = 1.0f / l;
#pragma unroll
    for (int dt = 0; dt < 2; dt++) {
#pragma unroll
      for (int r = 0; r < 16; r++) {
        const int d = dt * 32 + (r & 3) + 8 * (r >> 2) + 4 * hl;
        Cw[(qg * 32 + l31) * 72 + d] = bf16rne(co[qg][dt][r] * inv);
      }
    }
  }
  __syncthreads();
#pragma unroll
  for (int it = 0; it < 8; it++) {
    const int q = it * 8 + (lane >> 3);
    const int seg = lane & 7;
    const u32x4 o = *(const u32x4*)(Cw + q * 72 + seg * 8);
    *(u32x4*)(ctxr + (size_t)(b * 2048 + qrow0 + q) * 1024 + h * 64 + seg * 8) = o;
  }
}

// ---------------------------------------------------------------------------
extern "C" void kernel_launch(void* const* d_in, const int* in_sizes, int n_in,
                              void* d_out, int out_size, void* d_ws, size_t ws_size,
                              hipStream_t stream) {
  const float* Q = (const float*)d_in[0];
  const float* K = (const float*)d_in[1];
  const float* V = (const float*)d_in[2];
  const float* WQ = (const float*)d_in[3];
  const float* WK = (const float*)d_in[4];
  const float* WV = (const float*)d_in[5];
  const float* Wfc = (const float*)d_in[6];
  float* out = (float*)d_out;

  unsigned short* ws = (unsigned short*)d_ws;
  // ws layout (ushort units):
  //   Xb   @ 0         : 3*8388608  (bf16 Q,K,V)      [dead after projections]
  //   ctxr @ 0         : 8388608    (bf16 ctx)        [overlays Xb]
  //   Vt   @ 8388608   : 8388608    (f16 V^T)         [overlays Xb]
  //   Wt   @ 25165824  : 4*1048576  (bf16 W^T: q,k,v,fc)
  //   lin  @ 29360128  : 3*8388608  (bf16 projections)
  unsigned short* Xb = ws;
  unsigned short* ctxr = ws;
  unsigned short* Vt = ws + 8388608;
  unsigned short* Wt = ws + 25165824;
  unsigned short* lin = ws + 29360128;

  convert_x_kernel<<<dim3(4096, 3), 256, 0, stream>>>(Q, K, V, Xb);
  convert_w_kernel<<<dim3(32, 32, 4), 256, 0, stream>>>(WQ, WK, WV, Wfc, Wt);
  const float qscale = 0.125f * 1.4426950408889634f;  // 1/sqrt(dk) * log2(e)
  gemm_bt_kernel<<<dim3(64, 8, 3), 256, 0, stream>>>(Xb, Wt, lin, nullptr, qscale);
  vtrans_kernel<<<dim3(16, 64), 256, 0, stream>>>(lin + 16777216, Vt);
  attn_kernel<<<dim3(64, 8), 256, 0, stream>>>(lin, (const _Float16*)Vt, ctxr);
  gemm_bt_kernel<<<dim3(64, 8, 1), 256, 0, stream>>>(ctxr, Wt + 3 * 1048576, nullptr,
                                                     out, 1.0f);
}

// Round 10
// 358.844 us; speedup vs baseline: 1.0075x; 1.0075x over previous
//
#include <hip/hip_runtime.h>
#include <stdint.h>
#include <math.h>

// ---------------------------------------------------------------------------
// MultiHeadAttention: B=4, S=2048, D=1024, H=16, dk=64
// Raw-reshape head split: head (b,h) = rows [b*2048+h*128, +128) of the
// projected [8192][1024] matrix, reinterpreted as [2048][64].
// R11 (resubmit; prior run died to container infra, no data) = best-of-both:
// R9's BK=32 GEMM (R10's BK=64 regressed ~17us: halving barriers doesn't
// help when the vmcnt(0) drain still directly follows the staging loads --
// stall per iter doubles as iters halve; +64 VGPR fragment footprint) +
// R10's attention (z16-as-C-in first MFMA, v_max3 tree, native v_exp_f32
// softmax: verified -8.3us).
// Attn structure: 64 q-rows/wave (2 qg of 32), grid (64,8) = 2 blocks/CU,
// 48KB LDS L2-resident regime (R6: 4 blocks/CU thrashes L2, fetch x4),
// 32x32x16 MFMA path, K/V fragments read once per tile shared by both qg,
// layout-proof P-through-LDS (PV operands share one addressing convention
// so unknown k-slot permutations cancel), pkrtz pack, defer-max THR=8,
// async global_load_lds double-buffered staging, one barrier/tile,
// LDS-transpose epilogue.
// ---------------------------------------------------------------------------

typedef __attribute__((ext_vector_type(8))) short short8;
typedef __attribute__((ext_vector_type(4))) float f32x4;
typedef __attribute__((ext_vector_type(16))) float f32x16;
typedef __attribute__((ext_vector_type(2))) unsigned int u32x2;
typedef __attribute__((ext_vector_type(4))) unsigned int u32x4;
typedef __attribute__((ext_vector_type(8))) _Float16 half8;

__device__ __forceinline__ unsigned short bf16rne(float f) {
  unsigned int u = __builtin_bit_cast(unsigned int, f);
  unsigned int r = u + 0x7FFFu + ((u >> 16) & 1u);
  return (unsigned short)(r >> 16);
}

// async global->LDS, 16B per lane. LDS dest must be wave-uniform base + lane*16.
__device__ __forceinline__ void gld_lds16(const void* g, void* l) {
  typedef __attribute__((address_space(3))) unsigned int lds_u32;
  typedef const __attribute__((address_space(1))) unsigned int glb_u32;
  __builtin_amdgcn_global_load_lds((glb_u32*)(uintptr_t)g,
                                   (lds_u32*)(unsigned int)(uintptr_t)l,
                                   16, 0, 0);
}

// pack two f32 -> one u32 of two f16 (RTZ, single v_cvt_pkrtz_f16_f32)
__device__ __forceinline__ unsigned pkrtz(float a, float b) {
  auto h = __builtin_amdgcn_cvt_pkrtz(a, b);  // __fp16 ext_vector_type(2)
  return __builtin_bit_cast(unsigned, h);
}

// bare v_exp_f32 (2^x); no -ffast-math in harness so exp2f() is OCML multi-op.
__device__ __forceinline__ float fexp2(float x) {
#if __has_builtin(__builtin_amdgcn_exp2f)
  return __builtin_amdgcn_exp2f(x);
#else
  float r;
  asm("v_exp_f32 %0, %1" : "=v"(r) : "v"(x));
  return r;
#endif
}

// single-instruction 3-input max
__device__ __forceinline__ float max3f(float a, float b, float c) {
  float r;
  asm("v_max3_f32 %0, %1, %2, %3" : "=v"(r) : "v"(a), "v"(b), "v"(c));
  return r;
}

// ---------------------------------------------------------------------------
// fp32 -> bf16 convert for Q,K,V   (3 x 8192 x 1024)
// ---------------------------------------------------------------------------
__global__ void convert_x_kernel(const float* __restrict__ Q,
                                 const float* __restrict__ K,
                                 const float* __restrict__ V,
                                 unsigned short* __restrict__ Xb) {
  const int z = blockIdx.y;
  const float* src = (z == 0) ? Q : (z == 1) ? K : V;
  const size_t i0 = ((size_t)blockIdx.x * 256 + threadIdx.x) * 8;
  const f32x4 a = *(const f32x4*)(src + i0);
  const f32x4 c = *(const f32x4*)(src + i0 + 4);
  u32x4 o;
  o[0] = (unsigned)bf16rne(a[0]) | ((unsigned)bf16rne(a[1]) << 16);
  o[1] = (unsigned)bf16rne(a[2]) | ((unsigned)bf16rne(a[3]) << 16);
  o[2] = (unsigned)bf16rne(c[0]) | ((unsigned)bf16rne(c[1]) << 16);
  o[3] = (unsigned)bf16rne(c[2]) | ((unsigned)bf16rne(c[3]) << 16);
  *(u32x4*)(Xb + (size_t)z * 8388608 + i0) = o;
}

// ---------------------------------------------------------------------------
// W [K=1024][N=1024] fp32 -> Wt [N][K] bf16 (transposed so GEMMs are A*B^T)
// ---------------------------------------------------------------------------
__global__ void convert_w_kernel(const float* __restrict__ W0,
                                 const float* __restrict__ W1,
                                 const float* __restrict__ W2,
                                 const float* __restrict__ W3,
                                 unsigned short* __restrict__ Wt) {
  const int z = blockIdx.z;
  const float* W = (z == 0) ? W0 : (z == 1) ? W1 : (z == 2) ? W2 : W3;
  unsigned short* dst = Wt + (size_t)z * 1048576;
  __shared__ float tile[32][33];
  const int tx = threadIdx.x & 31, ty = threadIdx.x >> 5;
  const int k0 = blockIdx.x * 32, n0 = blockIdx.y * 32;
#pragma unroll
  for (int yy = 0; yy < 32; yy += 8)
    tile[ty + yy][tx] = W[(size_t)(k0 + ty + yy) * 1024 + n0 + tx];
  __syncthreads();
#pragma unroll
  for (int yy = 0; yy < 32; yy += 8)
    dst[(size_t)(n0 + ty + yy) * 1024 + k0 + tx] = bf16rne(tile[tx][ty + yy]);
}

// ---------------------------------------------------------------------------
// GEMM (m97 structure, BK=32 -- proven fastest in-session):
// C[z] = A[z][8192x1024] * Bt[z][1024x1024]^T
// ---------------------------------------------------------------------------
__global__ __launch_bounds__(256, 2) void gemm_bt_kernel(
    const unsigned short* __restrict__ A, const unsigned short* __restrict__ Bt,
    unsigned short* __restrict__ Cbf, float* __restrict__ Cf32, float scaleZ0) {
  constexpr int K = 1024, N = 1024;
  const int z = blockIdx.z;
  const unsigned short* Ab = A + (size_t)z * 8192 * 1024;
  const unsigned short* Bb = Bt + (size_t)z * 1024 * 1024;
  const int tid = threadIdx.x;
  const int lane = tid & 63;
  const int w = tid >> 6;
  const int l15 = lane & 15, quad = lane >> 4;
  const int rowBase = blockIdx.x * 128;
  const int colBase = blockIdx.y * 128;
  const int wrow = (w >> 1) * 64;
  const int wcol = (w & 1) * 64;
  __shared__ __align__(16) unsigned short As[128 * 32];
  __shared__ __align__(16) unsigned short Bs[128 * 32];

  const f32x4 z4 = {0.0f, 0.0f, 0.0f, 0.0f};
  f32x4 acc[4][4];
#pragma unroll
  for (int i = 0; i < 4; i++)
#pragma unroll
    for (int j = 0; j < 4; j++) acc[i][j] = z4;

  const int s0 = tid, s1 = tid + 256;
  const int rA0 = s0 >> 2, cA0 = (s0 & 3) * 8;
  const int rA1 = s1 >> 2, cA1 = (s1 & 3) * 8;

  for (int k0 = 0; k0 < K; k0 += 32) {
    gld_lds16(Ab + (size_t)(rowBase + rA0) * K + k0 + cA0, (void*)(As + s0 * 8));
    gld_lds16(Ab + (size_t)(rowBase + rA1) * K + k0 + cA1, (void*)(As + s1 * 8));
    gld_lds16(Bb + (size_t)(colBase + rA0) * K + k0 + cA0, (void*)(Bs + s0 * 8));
    gld_lds16(Bb + (size_t)(colBase + rA1) * K + k0 + cA1, (void*)(Bs + s1 * 8));
    __syncthreads();
    short8 af[4], bfr[4];
#pragma unroll
    for (int i = 0; i < 4; i++)
      af[i] = *(const short8*)(As + (wrow + i * 16 + l15) * 32 + quad * 8);
#pragma unroll
    for (int j = 0; j < 4; j++)
      bfr[j] = *(const short8*)(Bs + (wcol + j * 16 + l15) * 32 + quad * 8);
#pragma unroll
    for (int i = 0; i < 4; i++)
#pragma unroll
      for (int j = 0; j < 4; j++)
        acc[i][j] =
            __builtin_amdgcn_mfma_f32_16x16x32_bf16(af[i], bfr[j], acc[i][j], 0, 0, 0);
    __syncthreads();
  }

  const float sc = (z == 0) ? scaleZ0 : 1.0f;
#pragma unroll
  for (int i = 0; i < 4; i++) {
#pragma unroll
    for (int j = 0; j < 4; j++) {
#pragma unroll
      for (int r = 0; r < 4; r++) {
        const int row = rowBase + wrow + i * 16 + quad * 4 + r;
        const int col = colBase + wcol + j * 16 + l15;
        const float v = acc[i][j][r] * sc;
        if (Cbf != nullptr) {
          Cbf[(size_t)z * 8192 * 1024 + (size_t)row * N + col] = bf16rne(v);
        } else {
          Cf32[(size_t)row * N + col] = v;
        }
      }
    }
  }
}

// ---------------------------------------------------------------------------
// V transpose: lin_v head (b,h) [2048][64] bf16 -> Vt[bh][64][2048] f16.
// ---------------------------------------------------------------------------
__global__ void vtrans_kernel(const unsigned short* __restrict__ linv,
                              unsigned short* __restrict__ Vt) {
  const int st = blockIdx.x, bh = blockIdx.y;
  const unsigned short* vp = linv + (size_t)bh * 131072;
  __shared__ unsigned short tile[64 * 136];
  const int tid = threadIdx.x;
#pragma unroll
  for (int it = 0; it < 4; it++) {
    const int idx = it * 256 + tid;        // 0..1023
    const int s = idx >> 3, d0 = (idx & 7) * 8;
    const u32x4 vv = *(const u32x4*)(vp + (size_t)(st * 128 + s) * 64 + d0);
#pragma unroll
    for (int m = 0; m < 4; m++) {
      const unsigned lo = vv[m] & 0xffffu, hi = vv[m] >> 16;
      const float f0 = __builtin_bit_cast(float, lo << 16);
      const float f1 = __builtin_bit_cast(float, hi << 16);
      const _Float16 h0 = (_Float16)f0, h1 = (_Float16)f1;
      tile[(d0 + 2 * m) * 136 + s] = __builtin_bit_cast(unsigned short, h0);
      tile[(d0 + 2 * m + 1) * 136 + s] = __builtin_bit_cast(unsigned short, h1);
    }
  }
  __syncthreads();
#pragma unroll
  for (int it = 0; it < 4; it++) {
    const int idx = it * 256 + tid;
    const int d = idx >> 4, s0 = (idx & 15) * 8;
    const u32x4 o = *(const u32x4*)(tile + d * 136 + s0);
    *(u32x4*)(Vt + (size_t)bh * 131072 + (size_t)d * 2048 + st * 128 + s0) = o;
  }
}

// ---------------------------------------------------------------------------
// Flash attention, 32x32 MFMA path, async-LDS double-buffered, 64 q/wave.
// Grid (bh=64, qt=8); block 256 = 4 waves; wave w owns q-rows
// [qt*256 + w*64, +64) as two q-groups qg=0,1 of 32; lane's q = qg*32+l31.
// LDS 48KB (2 resident blocks/CU -- L2-resident regime; DO NOT raise
// blocks/CU: R6 thrashed L2, fetch 45->198MB).
// Ks [2][64 key][64 dk] bf16 16KB + Vs [2][64 d][64 key] f16 16KB (both
// XOR-swizzled 16B segs, seg^(row&7)) + per-wave P tile [32 q][64 key] f16
// 4KB x4 = 16KB (reused across qg; same-wave LDS is in-order).
// S^T = mfma_32x32x16_bf16(K, Q): C col = q = l31, row = key =
// (r&3)+8*(r>>2)+4*(l>>5)  [HW-verified layout]. First MFMA of each tile
// uses the persistent zero f32x16 as C-in (no per-tile acc zeroing).
// K/V fragments read ONCE per tile, used by both q-groups.
// PV per 32-key group g: P packed (pkrtz) and ds_written at its true key
// index, read back as B-fragments with the SAME convention as the V
// A-fragments (unknown k-slot permutations cancel between PV operands).
// ---------------------------------------------------------------------------
__global__ __launch_bounds__(256, 2) void attn_kernel(
    const unsigned short* __restrict__ lin, const _Float16* __restrict__ Vt,
    unsigned short* __restrict__ ctxr) {
  const int bh = blockIdx.x;
  const int qt = blockIdx.y;
  const int b = bh >> 4, h = bh & 15;
  const int tid = threadIdx.x, lane = tid & 63, w = tid >> 6;
  const int l31 = lane & 31, hl = lane >> 5, x7 = l31 & 7;
  const size_t headOff = (size_t)(b * 2048 + h * 128) * 1024;
  const unsigned short* qp = lin + headOff;
  const unsigned short* kp = lin + 8388608 + headOff;
  const _Float16* vtp = Vt + (size_t)bh * 131072;

  __shared__ __align__(16) unsigned short smem[24576];  // 48 KB
  unsigned short(*Ks)[4096] = (unsigned short(*)[4096])smem;     // [2][4096]
  _Float16(*Vs)[4096] = (_Float16(*)[4096])(smem + 8192);        // [2][4096]
  _Float16* Pl = (_Float16*)(smem + 16384) + w * 2048;           // [32][64]

  // Staging geometry: waves 0,1 stage K (512 slots); waves 2,3 stage V.
  const int stageV = (w >= 2);
  const int wbase = (stageV ? (w - 2) : w) * 256 + lane;
  auto stage = [&](int bufn, int key0) {
#pragma unroll
    for (int i = 0; i < 4; i++) {
      const int slot = wbase + i * 64;
      const int row = slot >> 3;                 // key (K) or d (V)
      const int seg = (slot & 7) ^ (row & 7);    // un-swizzled segment
      if (!stageV) {
        gld_lds16(kp + (size_t)(key0 + row) * 64 + seg * 8,
                  (void*)(&Ks[bufn][slot * 8]));
      } else {
        gld_lds16(vtp + (size_t)row * 2048 + key0 + seg * 8,
                  (void*)(&Vs[bufn][slot * 8]));
      }
    }
  };

  // Q B-fragments (col = q = l31, k-window ks*16 + hl*8) for both q-groups.
  const int qrow0 = qt * 256 + w * 64;
  short8 bq[2][4];
#pragma unroll
  for (int qg = 0; qg < 2; qg++)
#pragma unroll
    for (int ks = 0; ks < 4; ks++)
      bq[qg][ks] = *(const short8*)(qp +
                                    (size_t)(qrow0 + qg * 32 + l31) * 64 +
                                    ks * 16 + hl * 8);

  f32x16 z16;
#pragma unroll
  for (int r = 0; r < 16; r++) z16[r] = 0.0f;
  f32x16 co[2][2] = {{z16, z16}, {z16, z16}};  // [qg][dt]
  float mrun[2] = {-INFINITY, -INFINITY};
  float lrun[2] = {0.0f, 0.0f};

  stage(0, 0);
  __syncthreads();

  for (int kt = 0; kt < 32; kt++) {
    const int cur = kt & 1;
    if (kt < 31) stage(cur ^ 1, (kt + 1) * 64);

    // ---- K fragments ONCE (8x ds_read_b128), shared by both q-groups.
    short8 kf[2][4];
#pragma unroll
    for (int g = 0; g < 2; g++)
#pragma unroll
      for (int ks = 0; ks < 4; ks++) {
        const int slot = (g * 32 + l31) * 8 + ((2 * ks + hl) ^ x7);
        kf[g][ks] = *(const short8*)(&Ks[cur][slot * 8]);
      }

    // ---- S^T: 16x mfma_32x32x16_bf16; ks=0 takes z16 as C-in (no zeroing).
    f32x16 sacc[2][2];  // [qg][g]
    __builtin_amdgcn_s_setprio(1);
#pragma unroll
    for (int qg = 0; qg < 2; qg++)
#pragma unroll
      for (int g = 0; g < 2; g++) {
        sacc[qg][g] = __builtin_amdgcn_mfma_f32_32x32x16_bf16(
            kf[g][0], bq[qg][0], z16, 0, 0, 0);
#pragma unroll
        for (int ks = 1; ks < 4; ks++)
          sacc[qg][g] = __builtin_amdgcn_mfma_f32_32x32x16_bf16(
              kf[g][ks], bq[qg][ks], sacc[qg][g], 0, 0, 0);
      }
    __builtin_amdgcn_s_setprio(0);

    // ---- V A-fragments ONCE (8x ds_read_b128), shared by both q-groups.
    half8 vf[2][2][2];  // [dt][g][s]
#pragma unroll
    for (int dt = 0; dt < 2; dt++)
#pragma unroll
      for (int g = 0; g < 2; g++)
#pragma unroll
        for (int s = 0; s < 2; s++) {
          const int slot = (dt * 32 + l31) * 8 + ((4 * g + 2 * s + hl) ^ x7);
          vf[dt][g][s] = *(const half8*)(&Vs[cur][slot * 8]);
        }

    // ---- per q-group: softmax + P pack/write/read + PV
#pragma unroll
    for (int qg = 0; qg < 2; qg++) {
      float pmax;
      {
        float tm[8];
#pragma unroll
        for (int r = 0; r < 8; r++)
          tm[r] = fmaxf(max3f(sacc[qg][0][r], sacc[qg][0][r + 8],
                              sacc[qg][1][r]),
                        sacc[qg][1][r + 8]);
        const float a0 = max3f(tm[0], tm[1], tm[2]);
        const float a1 = max3f(tm[3], tm[4], tm[5]);
        const float a2 = fmaxf(tm[6], tm[7]);
        pmax = max3f(a0, a1, a2);
      }
      pmax = fmaxf(pmax, __shfl_xor(pmax, 32, 64));
      if (!__all(pmax - mrun[qg] <= 8.0f)) {  // defer-max
        const float mnew = fmaxf(mrun[qg], pmax);
        const float a = fexp2(mrun[qg] - mnew);
        mrun[qg] = mnew;
        lrun[qg] *= a;
#pragma unroll
        for (int r = 0; r < 16; r++) {
          co[qg][0][r] *= a;
          co[qg][1][r] *= a;
        }
      }
      float ls0 = 0.0f, ls1 = 0.0f, ls2 = 0.0f, ls3 = 0.0f;
#pragma unroll
      for (int g = 0; g < 2; g++) {
#pragma unroll
        for (int r = 0; r < 16; r += 4) {
          const float p0 = fexp2(sacc[qg][g][r + 0] - mrun[qg]);
          const float p1 = fexp2(sacc[qg][g][r + 1] - mrun[qg]);
          const float p2 = fexp2(sacc[qg][g][r + 2] - mrun[qg]);
          const float p3 = fexp2(sacc[qg][g][r + 3] - mrun[qg]);
          sacc[qg][g][r + 0] = p0;
          sacc[qg][g][r + 1] = p1;
          sacc[qg][g][r + 2] = p2;
          sacc[qg][g][r + 3] = p3;
          ls0 += p0;
          ls1 += p1;
          ls2 += p2;
          ls3 += p3;
        }
      }
      lrun[qg] += (ls0 + ls1) + (ls2 + ls3);

      // P -> per-wave LDS tile at true key index (C-layout key_in_grp =
      // 8rg+4hl+t), then B-fragments with the V A-fragment convention;
      // g's MFMAs overlap g+1's pack. Pl reused across qg (in-order LDS).
#pragma unroll
      for (int g = 0; g < 2; g++) {
#pragma unroll
        for (int rg = 0; rg < 4; rg++) {
          u32x2 pw;
          pw[0] = pkrtz(sacc[qg][g][4 * rg + 0], sacc[qg][g][4 * rg + 1]);
          pw[1] = pkrtz(sacc[qg][g][4 * rg + 2], sacc[qg][g][4 * rg + 3]);
          *(u32x2*)(Pl + l31 * 64 + (((4 * g + rg) ^ x7) * 8) + hl * 4) = pw;
        }
        half8 pf[2];
#pragma unroll
        for (int s = 0; s < 2; s++)
          pf[s] =
              *(const half8*)(Pl + l31 * 64 + (((4 * g + 2 * s + hl) ^ x7) * 8));
        __builtin_amdgcn_s_setprio(1);
#pragma unroll
        for (int dt = 0; dt < 2; dt++)
#pragma unroll
          for (int s = 0; s < 2; s++)
            co[qg][dt] = __builtin_amdgcn_mfma_f32_32x32x16_f16(
                vf[dt][g][s], pf[s], co[qg][dt], 0, 0, 0);
        __builtin_amdgcn_s_setprio(0);
      }
    }
    __syncthreads();  // drains stage loads; separates buffer reuse
  }

  // ---- epilogue: normalize, transpose via LDS, coalesced b128 stores.
  unsigned short* Cw = smem + w * 4608;  // per-wave 64 rows x stride 72
#pragma unroll
  for (int qg = 0; qg < 2; qg++) {
    const float l = lrun[qg] + __shfl_xor(lrun[qg], 32, 64);
    const float inv = 1.0f / l;
#pragma unroll
    for (int dt = 0; dt < 2; dt++) {
#pragma unroll
      for (int r = 0; r < 16; r++) {
        const int d = dt * 32 + (r & 3) + 8 * (r >> 2) + 4 * hl;
        Cw[(qg * 32 + l31) * 72 + d] = bf16rne(co[qg][dt][r] * inv);
      }
    }
  }
  __syncthreads();
#pragma unroll
  for (int it = 0; it < 8; it++) {
    const int q = it * 8 + (lane >> 3);
    const int seg = lane & 7;
    const u32x4 o = *(const u32x4*)(Cw + q * 72 + seg * 8);
    *(u32x4*)(ctxr + (size_t)(b * 2048 + qrow0 + q) * 1024 + h * 64 + seg * 8) = o;
  }
}

// ---------------------------------------------------------------------------
extern "C" void kernel_launch(void* const* d_in, const int* in_sizes, int n_in,
                              void* d_out, int out_size, void* d_ws, size_t ws_size,
                              hipStream_t stream) {
  const float* Q = (const float*)d_in[0];
  const float* K = (const float*)d_in[1];
  const float* V = (const float*)d_in[2];
  const float* WQ = (const float*)d_in[3];
  const float* WK = (const float*)d_in[4];
  const float* WV = (const float*)d_in[5];
  const float* Wfc = (const float*)d_in[6];
  float* out = (float*)d_out;

  unsigned short* ws = (unsigned short*)d_ws;
  // ws layout (ushort units):
  //   Xb   @ 0         : 3*8388608  (bf16 Q,K,V)      [dead after projections]
  //   ctxr @ 0         : 8388608    (bf16 ctx)        [overlays Xb]
  //   Vt   @ 8388608   : 8388608    (f16 V^T)         [overlays Xb]
  //   Wt   @ 25165824  : 4*1048576  (bf16 W^T: q,k,v,fc)
  //   lin  @ 29360128  : 3*8388608  (bf16 projections)
  unsigned short* Xb = ws;
  unsigned short* ctxr = ws;
  unsigned short* Vt = ws + 8388608;
  unsigned short* Wt = ws + 25165824;
  unsigned short* lin = ws + 29360128;

  convert_x_kernel<<<dim3(4096, 3), 256, 0, stream>>>(Q, K, V, Xb);
  convert_w_kernel<<<dim3(32, 32, 4), 256, 0, stream>>>(WQ, WK, WV, Wfc, Wt);
  const float qscale = 0.125f * 1.4426950408889634f;  // 1/sqrt(dk) * log2(e)
  gemm_bt_kernel<<<dim3(64, 8, 3), 256, 0, stream>>>(Xb, Wt, lin, nullptr, qscale);
  vtrans_kernel<<<dim3(16, 64), 256, 0, stream>>>(lin + 16777216, Vt);
  attn_kernel<<<dim3(64, 8), 256, 0, stream>>>(lin, (const _Float16*)Vt, ctxr);
  gemm_bt_kernel<<<dim3(64, 8, 1), 256, 0, stream>>>(ctxr, Wt + 3 * 1048576, nullptr,
                                                     out, 1.0f);
}

// Round 11
// 353.836 us; speedup vs baseline: 1.0218x; 1.0142x over previous
//
#include <hip/hip_runtime.h>
#include <stdint.h>
#include <math.h>

// ---------------------------------------------------------------------------
// MultiHeadAttention: B=4, S=2048, D=1024, H=16, dk=64
// Raw-reshape head split: head (b,h) = rows [b*2048+h*128, +128) of the
// projected [8192][1024] matrix, reinterpreted as [2048][64].
// R12 = R11 + GEMM pipeline fix (attn-proven pattern ported to gemm_bt):
//   - double-buffered LDS (As[2]/Bs[2], 32KB) with ONE barrier per K-step:
//     stage(next buf) issues first, then frag reads + 16 MFMA run BEFORE the
//     end-of-iteration vmcnt drain -> HBM latency self-hides under compute
//     (the old stage->barrier->compute had the full drain exposed).
//   - __launch_bounds__(256,3): 12 waves/CU (m97-reference occupancy) vs the
//     old cap of 8; more TLP across the remaining drain.
//   BK stays 32 (R10 showed BK=64 regresses: bigger frag footprint, same
//   exposed drain). Attn kernel unchanged from R11 (121.8us).
// Attn structure: 64 q-rows/wave (2 qg of 32), grid (64,8) = 2 blocks/CU,
// 48KB LDS L2-resident regime (R6: 4 blocks/CU thrashes L2, fetch x4),
// 32x32x16 MFMA path, K/V fragments read once per tile shared by both qg,
// layout-proof P-through-LDS, pkrtz pack, defer-max THR=8, native
// v_exp_f32 softmax, z16-as-C-in, v_max3 tree, async gld_lds dbuf staging,
// one barrier/tile, LDS-transpose epilogue.
// ---------------------------------------------------------------------------

typedef __attribute__((ext_vector_type(8))) short short8;
typedef __attribute__((ext_vector_type(4))) float f32x4;
typedef __attribute__((ext_vector_type(16))) float f32x16;
typedef __attribute__((ext_vector_type(2))) unsigned int u32x2;
typedef __attribute__((ext_vector_type(4))) unsigned int u32x4;
typedef __attribute__((ext_vector_type(8))) _Float16 half8;

__device__ __forceinline__ unsigned short bf16rne(float f) {
  unsigned int u = __builtin_bit_cast(unsigned int, f);
  unsigned int r = u + 0x7FFFu + ((u >> 16) & 1u);
  return (unsigned short)(r >> 16);
}

// async global->LDS, 16B per lane. LDS dest must be wave-uniform base + lane*16.
__device__ __forceinline__ void gld_lds16(const void* g, void* l) {
  typedef __attribute__((address_space(3))) unsigned int lds_u32;
  typedef const __attribute__((address_space(1))) unsigned int glb_u32;
  __builtin_amdgcn_global_load_lds((glb_u32*)(uintptr_t)g,
                                   (lds_u32*)(unsigned int)(uintptr_t)l,
                                   16, 0, 0);
}

// pack two f32 -> one u32 of two f16 (RTZ, single v_cvt_pkrtz_f16_f32)
__device__ __forceinline__ unsigned pkrtz(float a, float b) {
  auto h = __builtin_amdgcn_cvt_pkrtz(a, b);  // __fp16 ext_vector_type(2)
  return __builtin_bit_cast(unsigned, h);
}

// bare v_exp_f32 (2^x); no -ffast-math in harness so exp2f() is OCML multi-op.
__device__ __forceinline__ float fexp2(float x) {
#if __has_builtin(__builtin_amdgcn_exp2f)
  return __builtin_amdgcn_exp2f(x);
#else
  float r;
  asm("v_exp_f32 %0, %1" : "=v"(r) : "v"(x));
  return r;
#endif
}

// single-instruction 3-input max
__device__ __forceinline__ float max3f(float a, float b, float c) {
  float r;
  asm("v_max3_f32 %0, %1, %2, %3" : "=v"(r) : "v"(a), "v"(b), "v"(c));
  return r;
}

// ---------------------------------------------------------------------------
// fp32 -> bf16 convert for Q,K,V   (3 x 8192 x 1024)
// ---------------------------------------------------------------------------
__global__ void convert_x_kernel(const float* __restrict__ Q,
                                 const float* __restrict__ K,
                                 const float* __restrict__ V,
                                 unsigned short* __restrict__ Xb) {
  const int z = blockIdx.y;
  const float* src = (z == 0) ? Q : (z == 1) ? K : V;
  const size_t i0 = ((size_t)blockIdx.x * 256 + threadIdx.x) * 8;
  const f32x4 a = *(const f32x4*)(src + i0);
  const f32x4 c = *(const f32x4*)(src + i0 + 4);
  u32x4 o;
  o[0] = (unsigned)bf16rne(a[0]) | ((unsigned)bf16rne(a[1]) << 16);
  o[1] = (unsigned)bf16rne(a[2]) | ((unsigned)bf16rne(a[3]) << 16);
  o[2] = (unsigned)bf16rne(c[0]) | ((unsigned)bf16rne(c[1]) << 16);
  o[3] = (unsigned)bf16rne(c[2]) | ((unsigned)bf16rne(c[3]) << 16);
  *(u32x4*)(Xb + (size_t)z * 8388608 + i0) = o;
}

// ---------------------------------------------------------------------------
// W [K=1024][N=1024] fp32 -> Wt [N][K] bf16 (transposed so GEMMs are A*B^T)
// ---------------------------------------------------------------------------
__global__ void convert_w_kernel(const float* __restrict__ W0,
                                 const float* __restrict__ W1,
                                 const float* __restrict__ W2,
                                 const float* __restrict__ W3,
                                 unsigned short* __restrict__ Wt) {
  const int z = blockIdx.z;
  const float* W = (z == 0) ? W0 : (z == 1) ? W1 : (z == 2) ? W2 : W3;
  unsigned short* dst = Wt + (size_t)z * 1048576;
  __shared__ float tile[32][33];
  const int tx = threadIdx.x & 31, ty = threadIdx.x >> 5;
  const int k0 = blockIdx.x * 32, n0 = blockIdx.y * 32;
#pragma unroll
  for (int yy = 0; yy < 32; yy += 8)
    tile[ty + yy][tx] = W[(size_t)(k0 + ty + yy) * 1024 + n0 + tx];
  __syncthreads();
#pragma unroll
  for (int yy = 0; yy < 32; yy += 8)
    dst[(size_t)(n0 + ty + yy) * 1024 + k0 + tx] = bf16rne(tile[tx][ty + yy]);
}

// ---------------------------------------------------------------------------
// GEMM (m97 tiling, BK=32, double-buffered LDS, ONE barrier per K-step):
// C[z] = A[z][8192x1024] * Bt[z][1024x1024]^T
// ---------------------------------------------------------------------------
__global__ __launch_bounds__(256, 3) void gemm_bt_kernel(
    const unsigned short* __restrict__ A, const unsigned short* __restrict__ Bt,
    unsigned short* __restrict__ Cbf, float* __restrict__ Cf32, float scaleZ0) {
  constexpr int K = 1024, N = 1024;
  const int z = blockIdx.z;
  const unsigned short* Ab = A + (size_t)z * 8192 * 1024;
  const unsigned short* Bb = Bt + (size_t)z * 1024 * 1024;
  const int tid = threadIdx.x;
  const int lane = tid & 63;
  const int w = tid >> 6;
  const int l15 = lane & 15, quad = lane >> 4;
  const int rowBase = blockIdx.x * 128;
  const int colBase = blockIdx.y * 128;
  const int wrow = (w >> 1) * 64;
  const int wcol = (w & 1) * 64;
  __shared__ __align__(16) unsigned short As[2][128 * 32];  // 16 KB
  __shared__ __align__(16) unsigned short Bs[2][128 * 32];  // 16 KB

  const f32x4 z4 = {0.0f, 0.0f, 0.0f, 0.0f};
  f32x4 acc[4][4];
#pragma unroll
  for (int i = 0; i < 4; i++)
#pragma unroll
    for (int j = 0; j < 4; j++) acc[i][j] = z4;

  const int s0 = tid, s1 = tid + 256;
  const int rA0 = s0 >> 2, cA0 = (s0 & 3) * 8;
  const int rA1 = s1 >> 2, cA1 = (s1 & 3) * 8;

  auto stage = [&](int buf, int k0) {
    gld_lds16(Ab + (size_t)(rowBase + rA0) * K + k0 + cA0,
              (void*)(As[buf] + s0 * 8));
    gld_lds16(Ab + (size_t)(rowBase + rA1) * K + k0 + cA1,
              (void*)(As[buf] + s1 * 8));
    gld_lds16(Bb + (size_t)(colBase + rA0) * K + k0 + cA0,
              (void*)(Bs[buf] + s0 * 8));
    gld_lds16(Bb + (size_t)(colBase + rA1) * K + k0 + cA1,
              (void*)(Bs[buf] + s1 * 8));
  };

  stage(0, 0);
  __syncthreads();

  for (int kt = 0; kt < K / 32; kt++) {
    const int buf = kt & 1;
    if (kt < K / 32 - 1) stage(buf ^ 1, (kt + 1) * 32);  // fly under MFMA
    short8 af[4], bfr[4];
#pragma unroll
    for (int i = 0; i < 4; i++)
      af[i] = *(const short8*)(As[buf] + (wrow + i * 16 + l15) * 32 + quad * 8);
#pragma unroll
    for (int j = 0; j < 4; j++)
      bfr[j] = *(const short8*)(Bs[buf] + (wcol + j * 16 + l15) * 32 + quad * 8);
#pragma unroll
    for (int i = 0; i < 4; i++)
#pragma unroll
      for (int j = 0; j < 4; j++)
        acc[i][j] =
            __builtin_amdgcn_mfma_f32_16x16x32_bf16(af[i], bfr[j], acc[i][j], 0, 0, 0);
    __syncthreads();  // drains stage loads; separates buffer reuse
  }

  const float sc = (z == 0) ? scaleZ0 : 1.0f;
#pragma unroll
  for (int i = 0; i < 4; i++) {
#pragma unroll
    for (int j = 0; j < 4; j++) {
#pragma unroll
      for (int r = 0; r < 4; r++) {
        const int row = rowBase + wrow + i * 16 + quad * 4 + r;
        const int col = colBase + wcol + j * 16 + l15;
        const float v = acc[i][j][r] * sc;
        if (Cbf != nullptr) {
          Cbf[(size_t)z * 8192 * 1024 + (size_t)row * N + col] = bf16rne(v);
        } else {
          Cf32[(size_t)row * N + col] = v;
        }
      }
    }
  }
}

// ---------------------------------------------------------------------------
// V transpose: lin_v head (b,h) [2048][64] bf16 -> Vt[bh][64][2048] f16.
// ---------------------------------------------------------------------------
__global__ void vtrans_kernel(const unsigned short* __restrict__ linv,
                              unsigned short* __restrict__ Vt) {
  const int st = blockIdx.x, bh = blockIdx.y;
  const unsigned short* vp = linv + (size_t)bh * 131072;
  __shared__ unsigned short tile[64 * 136];
  const int tid = threadIdx.x;
#pragma unroll
  for (int it = 0; it < 4; it++) {
    const int idx = it * 256 + tid;        // 0..1023
    const int s = idx >> 3, d0 = (idx & 7) * 8;
    const u32x4 vv = *(const u32x4*)(vp + (size_t)(st * 128 + s) * 64 + d0);
#pragma unroll
    for (int m = 0; m < 4; m++) {
      const unsigned lo = vv[m] & 0xffffu, hi = vv[m] >> 16;
      const float f0 = __builtin_bit_cast(float, lo << 16);
      const float f1 = __builtin_bit_cast(float, hi << 16);
      const _Float16 h0 = (_Float16)f0, h1 = (_Float16)f1;
      tile[(d0 + 2 * m) * 136 + s] = __builtin_bit_cast(unsigned short, h0);
      tile[(d0 + 2 * m + 1) * 136 + s] = __builtin_bit_cast(unsigned short, h1);
    }
  }
  __syncthreads();
#pragma unroll
  for (int it = 0; it < 4; it++) {
    const int idx = it * 256 + tid;
    const int d = idx >> 4, s0 = (idx & 15) * 8;
    const u32x4 o = *(const u32x4*)(tile + d * 136 + s0);
    *(u32x4*)(Vt + (size_t)bh * 131072 + (size_t)d * 2048 + st * 128 + s0) = o;
  }
}

// ---------------------------------------------------------------------------
// Flash attention, 32x32 MFMA path, async-LDS double-buffered, 64 q/wave.
// Grid (bh=64, qt=8); block 256 = 4 waves; wave w owns q-rows
// [qt*256 + w*64, +64) as two q-groups qg=0,1 of 32; lane's q = qg*32+l31.
// LDS 48KB (2 resident blocks/CU -- L2-resident regime; DO NOT raise
// blocks/CU: R6 thrashed L2, fetch 45->198MB).
// Ks [2][64 key][64 dk] bf16 16KB + Vs [2][64 d][64 key] f16 16KB (both
// XOR-swizzled 16B segs, seg^(row&7)) + per-wave P tile [32 q][64 key] f16
// 4KB x4 = 16KB (reused across qg; same-wave LDS is in-order).
// S^T = mfma_32x32x16_bf16(K, Q): C col = q = l31, row = key =
// (r&3)+8*(r>>2)+4*(l>>5)  [HW-verified layout]. First MFMA of each tile
// uses the persistent zero f32x16 as C-in (no per-tile acc zeroing).
// K/V fragments read ONCE per tile, used by both q-groups.
// PV per 32-key group g: P packed (pkrtz) and ds_written at its true key
// index, read back as B-fragments with the SAME convention as the V
// A-fragments (unknown k-slot permutations cancel between PV operands).
// ---------------------------------------------------------------------------
__global__ __launch_bounds__(256, 2) void attn_kernel(
    const unsigned short* __restrict__ lin, const _Float16* __restrict__ Vt,
    unsigned short* __restrict__ ctxr) {
  const int bh = blockIdx.x;
  const int qt = blockIdx.y;
  const int b = bh >> 4, h = bh & 15;
  const int tid = threadIdx.x, lane = tid & 63, w = tid >> 6;
  const int l31 = lane & 31, hl = lane >> 5, x7 = l31 & 7;
  const size_t headOff = (size_t)(b * 2048 + h * 128) * 1024;
  const unsigned short* qp = lin + headOff;
  const unsigned short* kp = lin + 8388608 + headOff;
  const _Float16* vtp = Vt + (size_t)bh * 131072;

  __shared__ __align__(16) unsigned short smem[24576];  // 48 KB
  unsigned short(*Ks)[4096] = (unsigned short(*)[4096])smem;     // [2][4096]
  _Float16(*Vs)[4096] = (_Float16(*)[4096])(smem + 8192);        // [2][4096]
  _Float16* Pl = (_Float16*)(smem + 16384) + w * 2048;           // [32][64]

  // Staging geometry: waves 0,1 stage K (512 slots); waves 2,3 stage V.
  const int stageV = (w >= 2);
  const int wbase = (stageV ? (w - 2) : w) * 256 + lane;
  auto stage = [&](int bufn, int key0) {
#pragma unroll
    for (int i = 0; i < 4; i++) {
      const int slot = wbase + i * 64;
      const int row = slot >> 3;                 // key (K) or d (V)
      const int seg = (slot & 7) ^ (row & 7);    // un-swizzled segment
      if (!stageV) {
        gld_lds16(kp + (size_t)(key0 + row) * 64 + seg * 8,
                  (void*)(&Ks[bufn][slot * 8]));
      } else {
        gld_lds16(vtp + (size_t)row * 2048 + key0 + seg * 8,
                  (void*)(&Vs[bufn][slot * 8]));
      }
    }
  };

  // Q B-fragments (col = q = l31, k-window ks*16 + hl*8) for both q-groups.
  const int qrow0 = qt * 256 + w * 64;
  short8 bq[2][4];
#pragma unroll
  for (int qg = 0; qg < 2; qg++)
#pragma unroll
    for (int ks = 0; ks < 4; ks++)
      bq[qg][ks] = *(const short8*)(qp +
                                    (size_t)(qrow0 + qg * 32 + l31) * 64 +
                                    ks * 16 + hl * 8);

  f32x16 z16;
#pragma unroll
  for (int r = 0; r < 16; r++) z16[r] = 0.0f;
  f32x16 co[2][2] = {{z16, z16}, {z16, z16}};  // [qg][dt]
  float mrun[2] = {-INFINITY, -INFINITY};
  float lrun[2] = {0.0f, 0.0f};

  stage(0, 0);
  __syncthreads();

  for (int kt = 0; kt < 32; kt++) {
    const int cur = kt & 1;
    if (kt < 31) stage(cur ^ 1, (kt + 1) * 64);

    // ---- K fragments ONCE (8x ds_read_b128), shared by both q-groups.
    short8 kf[2][4];
#pragma unroll
    for (int g = 0; g < 2; g++)
#pragma unroll
      for (int ks = 0; ks < 4; ks++) {
        const int slot = (g * 32 + l31) * 8 + ((2 * ks + hl) ^ x7);
        kf[g][ks] = *(const short8*)(&Ks[cur][slot * 8]);
      }

    // ---- S^T: 16x mfma_32x32x16_bf16; ks=0 takes z16 as C-in (no zeroing).
    f32x16 sacc[2][2];  // [qg][g]
    __builtin_amdgcn_s_setprio(1);
#pragma unroll
    for (int qg = 0; qg < 2; qg++)
#pragma unroll
      for (int g = 0; g < 2; g++) {
        sacc[qg][g] = __builtin_amdgcn_mfma_f32_32x32x16_bf16(
            kf[g][0], bq[qg][0], z16, 0, 0, 0);
#pragma unroll
        for (int ks = 1; ks < 4; ks++)
          sacc[qg][g] = __builtin_amdgcn_mfma_f32_32x32x16_bf16(
              kf[g][ks], bq[qg][ks], sacc[qg][g], 0, 0, 0);
      }
    __builtin_amdgcn_s_setprio(0);

    // ---- V A-fragments ONCE (8x ds_read_b128), shared by both q-groups.
    half8 vf[2][2][2];  // [dt][g][s]
#pragma unroll
    for (int dt = 0; dt < 2; dt++)
#pragma unroll
      for (int g = 0; g < 2; g++)
#pragma unroll
        for (int s = 0; s < 2; s++) {
          const int slot = (dt * 32 + l31) * 8 + ((4 * g + 2 * s + hl) ^ x7);
          vf[dt][g][s] = *(const half8*)(&Vs[cur][slot * 8]);
        }

    // ---- per q-group: softmax + P pack/write/read + PV
#pragma unroll
    for (int qg = 0; qg < 2; qg++) {
      float pmax;
      {
        float tm[8];
#pragma unroll
        for (int r = 0; r < 8; r++)
          tm[r] = fmaxf(max3f(sacc[qg][0][r], sacc[qg][0][r + 8],
                              sacc[qg][1][r]),
                        sacc[qg][1][r + 8]);
        const float a0 = max3f(tm[0], tm[1], tm[2]);
        const float a1 = max3f(tm[3], tm[4], tm[5]);
        const float a2 = fmaxf(tm[6], tm[7]);
        pmax = max3f(a0, a1, a2);
      }
      pmax = fmaxf(pmax, __shfl_xor(pmax, 32, 64));
      if (!__all(pmax - mrun[qg] <= 8.0f)) {  // defer-max
        const float mnew = fmaxf(mrun[qg], pmax);
        const float a = fexp2(mrun[qg] - mnew);
        mrun[qg] = mnew;
        lrun[qg] *= a;
#pragma unroll
        for (int r = 0; r < 16; r++) {
          co[qg][0][r] *= a;
          co[qg][1][r] *= a;
        }
      }
      float ls0 = 0.0f, ls1 = 0.0f, ls2 = 0.0f, ls3 = 0.0f;
#pragma unroll
      for (int g = 0; g < 2; g++) {
#pragma unroll
        for (int r = 0; r < 16; r += 4) {
          const float p0 = fexp2(sacc[qg][g][r + 0] - mrun[qg]);
          const float p1 = fexp2(sacc[qg][g][r + 1] - mrun[qg]);
          const float p2 = fexp2(sacc[qg][g][r + 2] - mrun[qg]);
          const float p3 = fexp2(sacc[qg][g][r + 3] - mrun[qg]);
          sacc[qg][g][r + 0] = p0;
          sacc[qg][g][r + 1] = p1;
          sacc[qg][g][r + 2] = p2;
          sacc[qg][g][r + 3] = p3;
          ls0 += p0;
          ls1 += p1;
          ls2 += p2;
          ls3 += p3;
        }
      }
      lrun[qg] += (ls0 + ls1) + (ls2 + ls3);

      // P -> per-wave LDS tile at true key index (C-layout key_in_grp =
      // 8rg+4hl+t), then B-fragments with the V A-fragment convention;
      // g's MFMAs overlap g+1's pack. Pl reused across qg (in-order LDS).
#pragma unroll
      for (int g = 0; g < 2; g++) {
#pragma unroll
        for (int rg = 0; rg < 4; rg++) {
          u32x2 pw;
          pw[0] = pkrtz(sacc[qg][g][4 * rg + 0], sacc[qg][g][4 * rg + 1]);
          pw[1] = pkrtz(sacc[qg][g][4 * rg + 2], sacc[qg][g][4 * rg + 3]);
          *(u32x2*)(Pl + l31 * 64 + (((4 * g + rg) ^ x7) * 8) + hl * 4) = pw;
        }
        half8 pf[2];
#pragma unroll
        for (int s = 0; s < 2; s++)
          pf[s] =
              *(const half8*)(Pl + l31 * 64 + (((4 * g + 2 * s + hl) ^ x7) * 8));
        __builtin_amdgcn_s_setprio(1);
#pragma unroll
        for (int dt = 0; dt < 2; dt++)
#pragma unroll
          for (int s = 0; s < 2; s++)
            co[qg][dt] = __builtin_amdgcn_mfma_f32_32x32x16_f16(
                vf[dt][g][s], pf[s], co[qg][dt], 0, 0, 0);
        __builtin_amdgcn_s_setprio(0);
      }
    }
    __syncthreads();  // drains stage loads; separates buffer reuse
  }

  // ---- epilogue: normalize, transpose via LDS, coalesced b128 stores.
  unsigned short* Cw = smem + w * 4608;  // per-wave 64 rows x stride 72
#pragma unroll
  for (int qg = 0; qg < 2; qg++) {
    const float l = lrun[qg] + __shfl_xor(lrun[qg], 32, 64);
    const float inv = 1.0f / l;
#pragma unroll
    for (int dt = 0; dt < 2; dt++) {
#pragma unroll
      for (int r = 0; r < 16; r++) {
        const int d = dt * 32 + (r & 3) + 8 * (r >> 2) + 4 * hl;
        Cw[(qg * 32 + l31) * 72 + d] = bf16rne(co[qg][dt][r] * inv);
      }
    }
  }
  __syncthreads();
#pragma unroll
  for (int it = 0; it < 8; it++) {
    const int q = it * 8 + (lane >> 3);
    const int seg = lane & 7;
    const u32x4 o = *(const u32x4*)(Cw + q * 72 + seg * 8);
    *(u32x4*)(ctxr + (size_t)(b * 2048 + qrow0 + q) * 1024 + h * 64 + seg * 8) = o;
  }
}

// ---------------------------------------------------------------------------
extern "C" void kernel_launch(void* const* d_in, const int* in_sizes, int n_in,
                              void* d_out, int out_size, void* d_ws, size_t ws_size,
                              hipStream_t stream) {
  const float* Q = (const float*)d_in[0];
  const float* K = (const float*)d_in[1];
  const float* V = (const float*)d_in[2];
  const float* WQ = (const float*)d_in[3];
  const float* WK = (const float*)d_in[4];
  const float* WV = (const float*)d_in[5];
  const float* Wfc = (const float*)d_in[6];
  float* out = (float*)d_out;

  unsigned short* ws = (unsigned short*)d_ws;
  // ws layout (ushort units):
  //   Xb   @ 0         : 3*8388608  (bf16 Q,K,V)      [dead after projections]
  //   ctxr @ 0         : 8388608    (bf16 ctx)        [overlays Xb]
  //   Vt   @ 8388608   : 8388608    (f16 V^T)         [overlays Xb]
  //   Wt   @ 25165824  : 4*1048576  (bf16 W^T: q,k,v,fc)
  //   lin  @ 29360128  : 3*8388608  (bf16 projections)
  unsigned short* Xb = ws;
  unsigned short* ctxr = ws;
  unsigned short* Vt = ws + 8388608;
  unsigned short* Wt = ws + 25165824;
  unsigned short* lin = ws + 29360128;

  convert_x_kernel<<<dim3(4096, 3), 256, 0, stream>>>(Q, K, V, Xb);
  convert_w_kernel<<<dim3(32, 32, 4), 256, 0, stream>>>(WQ, WK, WV, Wfc, Wt);
  const float qscale = 0.125f * 1.4426950408889634f;  // 1/sqrt(dk) * log2(e)
  gemm_bt_kernel<<<dim3(64, 8, 3), 256, 0, stream>>>(Xb, Wt, lin, nullptr, qscale);
  vtrans_kernel<<<dim3(16, 64), 256, 0, stream>>>(lin + 16777216, Vt);
  attn_kernel<<<dim3(64, 8), 256, 0, stream>>>(lin, (const _Float16*)Vt, ctxr);
  gemm_bt_kernel<<<dim3(64, 8, 1), 256, 0, stream>>>(ctxr, Wt + 3 * 1048576, nullptr,
                                                     out, 1.0f);
}

// Round 13
// 348.393 us; speedup vs baseline: 1.0377x; 1.0156x over previous
//
#include <hip/hip_runtime.h>
#include <stdint.h>
#include <math.h>

// ---------------------------------------------------------------------------
// MultiHeadAttention: B=4, S=2048, D=1024, H=16, dk=64
// Raw-reshape head split: head (b,h) = rows [b*2048+h*128, +128) of the
// projected [8192][1024] matrix, reinterpreted as [2048][64].
// R13 (resubmit; prior run died to container infra, no data) = R12 attention
// (unchanged, 121us) + big-tile GEMM:
//   BM=256 x BN=128, 512 threads = 8 waves (4M x 2N), BK=64, double-buffered
//   LDS (96KB: As[2][256x64] + Bs[2][128x64]), ONE barrier per K-tile.
//   Per barrier-pair: 32 MFMA + 6 gld_lds per thread (2x the amortization of
//   the old 128^2/BK32 loop). Both-sides XOR swizzle for the 128B LDS rows
//   (pre-swizzled global source col seg^(row&7) + matching fragment-read
//   XOR (kk*4+quad)^(row&7)) -- correctness of this scheme verified in R10.
//   Grid tiles perfectly: proj (32,8,3)=768 blocks = 3 full CU rounds;
//   final (32,8)=256 = 1 round; no tail.
// Attn structure (unchanged): 64 q-rows/wave, grid (64,8) = 2 blocks/CU,
// 48KB LDS L2-resident regime (R6: more blocks thrashes L2, fetch x4),
// 32x32x16 MFMA path, K/V fragments once per tile shared by both qg,
// layout-proof P-through-LDS, pkrtz, defer-max THR=8, native v_exp_f32,
// z16-as-C-in, v_max3 tree, async gld_lds dbuf staging, 1 barrier/tile,
// LDS-transpose epilogue.
// ---------------------------------------------------------------------------

typedef __attribute__((ext_vector_type(8))) short short8;
typedef __attribute__((ext_vector_type(4))) float f32x4;
typedef __attribute__((ext_vector_type(16))) float f32x16;
typedef __attribute__((ext_vector_type(2))) unsigned int u32x2;
typedef __attribute__((ext_vector_type(4))) unsigned int u32x4;
typedef __attribute__((ext_vector_type(8))) _Float16 half8;

__device__ __forceinline__ unsigned short bf16rne(float f) {
  unsigned int u = __builtin_bit_cast(unsigned int, f);
  unsigned int r = u + 0x7FFFu + ((u >> 16) & 1u);
  return (unsigned short)(r >> 16);
}

// async global->LDS, 16B per lane. LDS dest must be wave-uniform base + lane*16.
__device__ __forceinline__ void gld_lds16(const void* g, void* l) {
  typedef __attribute__((address_space(3))) unsigned int lds_u32;
  typedef const __attribute__((address_space(1))) unsigned int glb_u32;
  __builtin_amdgcn_global_load_lds((glb_u32*)(uintptr_t)g,
                                   (lds_u32*)(unsigned int)(uintptr_t)l,
                                   16, 0, 0);
}

// pack two f32 -> one u32 of two f16 (RTZ, single v_cvt_pkrtz_f16_f32)
__device__ __forceinline__ unsigned pkrtz(float a, float b) {
  auto h = __builtin_amdgcn_cvt_pkrtz(a, b);  // __fp16 ext_vector_type(2)
  return __builtin_bit_cast(unsigned, h);
}

// bare v_exp_f32 (2^x); no -ffast-math in harness so exp2f() is OCML multi-op.
__device__ __forceinline__ float fexp2(float x) {
#if __has_builtin(__builtin_amdgcn_exp2f)
  return __builtin_amdgcn_exp2f(x);
#else
  float r;
  asm("v_exp_f32 %0, %1" : "=v"(r) : "v"(x));
  return r;
#endif
}

// single-instruction 3-input max
__device__ __forceinline__ float max3f(float a, float b, float c) {
  float r;
  asm("v_max3_f32 %0, %1, %2, %3" : "=v"(r) : "v"(a), "v"(b), "v"(c));
  return r;
}

// ---------------------------------------------------------------------------
// fp32 -> bf16 convert for Q,K,V   (3 x 8192 x 1024)
// ---------------------------------------------------------------------------
__global__ void convert_x_kernel(const float* __restrict__ Q,
                                 const float* __restrict__ K,
                                 const float* __restrict__ V,
                                 unsigned short* __restrict__ Xb) {
  const int z = blockIdx.y;
  const float* src = (z == 0) ? Q : (z == 1) ? K : V;
  const size_t i0 = ((size_t)blockIdx.x * 256 + threadIdx.x) * 8;
  const f32x4 a = *(const f32x4*)(src + i0);
  const f32x4 c = *(const f32x4*)(src + i0 + 4);
  u32x4 o;
  o[0] = (unsigned)bf16rne(a[0]) | ((unsigned)bf16rne(a[1]) << 16);
  o[1] = (unsigned)bf16rne(a[2]) | ((unsigned)bf16rne(a[3]) << 16);
  o[2] = (unsigned)bf16rne(c[0]) | ((unsigned)bf16rne(c[1]) << 16);
  o[3] = (unsigned)bf16rne(c[2]) | ((unsigned)bf16rne(c[3]) << 16);
  *(u32x4*)(Xb + (size_t)z * 8388608 + i0) = o;
}

// ---------------------------------------------------------------------------
// W [K=1024][N=1024] fp32 -> Wt [N][K] bf16 (transposed so GEMMs are A*B^T)
// ---------------------------------------------------------------------------
__global__ void convert_w_kernel(const float* __restrict__ W0,
                                 const float* __restrict__ W1,
                                 const float* __restrict__ W2,
                                 const float* __restrict__ W3,
                                 unsigned short* __restrict__ Wt) {
  const int z = blockIdx.z;
  const float* W = (z == 0) ? W0 : (z == 1) ? W1 : (z == 2) ? W2 : W3;
  unsigned short* dst = Wt + (size_t)z * 1048576;
  __shared__ float tile[32][33];
  const int tx = threadIdx.x & 31, ty = threadIdx.x >> 5;
  const int k0 = blockIdx.x * 32, n0 = blockIdx.y * 32;
#pragma unroll
  for (int yy = 0; yy < 32; yy += 8)
    tile[ty + yy][tx] = W[(size_t)(k0 + ty + yy) * 1024 + n0 + tx];
  __syncthreads();
#pragma unroll
  for (int yy = 0; yy < 32; yy += 8)
    dst[(size_t)(n0 + ty + yy) * 1024 + k0 + tx] = bf16rne(tile[tx][ty + yy]);
}

// ---------------------------------------------------------------------------
// GEMM: C[z] = A[z][8192x1024] * Bt[z][1024x1024]^T.
// BM=256 x BN=128, 512 thr = 8 waves (4M x 2N), BK=64, dbuf LDS 96KB,
// one barrier per K-tile (32 MFMA / 6 loads per thread per barrier).
// Both-sides XOR swizzle (128B rows): source col seg^(row&7) pre-applied at
// the global address, fragment read applies (kk*4+quad)^(row&7).
// A/B share the convention -> k-pairing is permutation-invariant (R10-proven).
// ---------------------------------------------------------------------------
__global__ __launch_bounds__(512, 1) void gemm_bt_kernel(
    const unsigned short* __restrict__ A, const unsigned short* __restrict__ Bt,
    unsigned short* __restrict__ Cbf, float* __restrict__ Cf32, float scaleZ0) {
  constexpr int K = 1024, N = 1024;
  const int z = blockIdx.z;
  const unsigned short* Ab = A + (size_t)z * 8192 * 1024;
  const unsigned short* Bb = Bt + (size_t)z * 1024 * 1024;
  const int tid = threadIdx.x;
  const int lane = tid & 63;
  const int w = tid >> 6;               // 0..7
  const int l15 = lane & 15, quad = lane >> 4;
  const int rowBase = blockIdx.x * 256;
  const int colBase = blockIdx.y * 128;
  const int wrow = (w >> 1) * 64;       // 4 M-bands
  const int wcol = (w & 1) * 64;        // 2 N-bands
  __shared__ __align__(16) unsigned short As[2][256 * 64];  // 64 KB
  __shared__ __align__(16) unsigned short Bs[2][128 * 64];  // 32 KB

  const f32x4 z4 = {0.0f, 0.0f, 0.0f, 0.0f};
  f32x4 acc[4][4];
#pragma unroll
  for (int i = 0; i < 4; i++)
#pragma unroll
    for (int j = 0; j < 4; j++) acc[i][j] = z4;

  auto stage = [&](int buf, int k0) {
#pragma unroll
    for (int it = 0; it < 4; it++) {  // A: 256 rows x 64 cols
      const int slot = it * 512 + tid;
      const int row = slot >> 3;
      const int sseg = (slot & 7) ^ (row & 7);
      gld_lds16(Ab + (size_t)(rowBase + row) * K + k0 + sseg * 8,
                (void*)(As[buf] + slot * 8));
    }
#pragma unroll
    for (int it = 0; it < 2; it++) {  // B: 128 rows x 64 cols
      const int slot = it * 512 + tid;
      const int row = slot >> 3;
      const int sseg = (slot & 7) ^ (row & 7);
      gld_lds16(Bb + (size_t)(colBase + row) * K + k0 + sseg * 8,
                (void*)(Bs[buf] + slot * 8));
    }
  };

  stage(0, 0);
  __syncthreads();

  for (int kt = 0; kt < K / 64; kt++) {
    const int buf = kt & 1;
    if (kt < K / 64 - 1) stage(buf ^ 1, (kt + 1) * 64);  // fly under MFMA
#pragma unroll
    for (int kk = 0; kk < 2; kk++) {
      short8 af[4], bfr[4];
#pragma unroll
      for (int i = 0; i < 4; i++) {
        const int row = wrow + i * 16 + l15;
        af[i] = *(const short8*)(As[buf] +
                                 (row * 8 + ((kk * 4 + quad) ^ (row & 7))) * 8);
      }
#pragma unroll
      for (int j = 0; j < 4; j++) {
        const int row = wcol + j * 16 + l15;
        bfr[j] = *(const short8*)(Bs[buf] +
                                  (row * 8 + ((kk * 4 + quad) ^ (row & 7))) * 8);
      }
#pragma unroll
      for (int i = 0; i < 4; i++)
#pragma unroll
        for (int j = 0; j < 4; j++)
          acc[i][j] = __builtin_amdgcn_mfma_f32_16x16x32_bf16(
              af[i], bfr[j], acc[i][j], 0, 0, 0);
    }
    __syncthreads();  // drains stage loads; separates buffer reuse
  }

  const float sc = (z == 0) ? scaleZ0 : 1.0f;
#pragma unroll
  for (int i = 0; i < 4; i++) {
#pragma unroll
    for (int j = 0; j < 4; j++) {
#pragma unroll
      for (int r = 0; r < 4; r++) {
        const int row = rowBase + wrow + i * 16 + quad * 4 + r;
        const int col = colBase + wcol + j * 16 + l15;
        const float v = acc[i][j][r] * sc;
        if (Cbf != nullptr) {
          Cbf[(size_t)z * 8192 * 1024 + (size_t)row * N + col] = bf16rne(v);
        } else {
          Cf32[(size_t)row * N + col] = v;
        }
      }
    }
  }
}

// ---------------------------------------------------------------------------
// V transpose: lin_v head (b,h) [2048][64] bf16 -> Vt[bh][64][2048] f16.
// ---------------------------------------------------------------------------
__global__ void vtrans_kernel(const unsigned short* __restrict__ linv,
                              unsigned short* __restrict__ Vt) {
  const int st = blockIdx.x, bh = blockIdx.y;
  const unsigned short* vp = linv + (size_t)bh * 131072;
  __shared__ unsigned short tile[64 * 136];
  const int tid = threadIdx.x;
#pragma unroll
  for (int it = 0; it < 4; it++) {
    const int idx = it * 256 + tid;        // 0..1023
    const int s = idx >> 3, d0 = (idx & 7) * 8;
    const u32x4 vv = *(const u32x4*)(vp + (size_t)(st * 128 + s) * 64 + d0);
#pragma unroll
    for (int m = 0; m < 4; m++) {
      const unsigned lo = vv[m] & 0xffffu, hi = vv[m] >> 16;
      const float f0 = __builtin_bit_cast(float, lo << 16);
      const float f1 = __builtin_bit_cast(float, hi << 16);
      const _Float16 h0 = (_Float16)f0, h1 = (_Float16)f1;
      tile[(d0 + 2 * m) * 136 + s] = __builtin_bit_cast(unsigned short, h0);
      tile[(d0 + 2 * m + 1) * 136 + s] = __builtin_bit_cast(unsigned short, h1);
    }
  }
  __syncthreads();
#pragma unroll
  for (int it = 0; it < 4; it++) {
    const int idx = it * 256 + tid;
    const int d = idx >> 4, s0 = (idx & 15) * 8;
    const u32x4 o = *(const u32x4*)(tile + d * 136 + s0);
    *(u32x4*)(Vt + (size_t)bh * 131072 + (size_t)d * 2048 + st * 128 + s0) = o;
  }
}

// ---------------------------------------------------------------------------
// Flash attention, 32x32 MFMA path, async-LDS double-buffered, 64 q/wave.
// (unchanged from R11/R12; see header comment)
// ---------------------------------------------------------------------------
__global__ __launch_bounds__(256, 2) void attn_kernel(
    const unsigned short* __restrict__ lin, const _Float16* __restrict__ Vt,
    unsigned short* __restrict__ ctxr) {
  const int bh = blockIdx.x;
  const int qt = blockIdx.y;
  const int b = bh >> 4, h = bh & 15;
  const int tid = threadIdx.x, lane = tid & 63, w = tid >> 6;
  const int l31 = lane & 31, hl = lane >> 5, x7 = l31 & 7;
  const size_t headOff = (size_t)(b * 2048 + h * 128) * 1024;
  const unsigned short* qp = lin + headOff;
  const unsigned short* kp = lin + 8388608 + headOff;
  const _Float16* vtp = Vt + (size_t)bh * 131072;

  __shared__ __align__(16) unsigned short smem[24576];  // 48 KB
  unsigned short(*Ks)[4096] = (unsigned short(*)[4096])smem;     // [2][4096]
  _Float16(*Vs)[4096] = (_Float16(*)[4096])(smem + 8192);        // [2][4096]
  _Float16* Pl = (_Float16*)(smem + 16384) + w * 2048;           // [32][64]

  // Staging geometry: waves 0,1 stage K (512 slots); waves 2,3 stage V.
  const int stageV = (w >= 2);
  const int wbase = (stageV ? (w - 2) : w) * 256 + lane;
  auto stage = [&](int bufn, int key0) {
#pragma unroll
    for (int i = 0; i < 4; i++) {
      const int slot = wbase + i * 64;
      const int row = slot >> 3;                 // key (K) or d (V)
      const int seg = (slot & 7) ^ (row & 7);    // un-swizzled segment
      if (!stageV) {
        gld_lds16(kp + (size_t)(key0 + row) * 64 + seg * 8,
                  (void*)(&Ks[bufn][slot * 8]));
      } else {
        gld_lds16(vtp + (size_t)row * 2048 + key0 + seg * 8,
                  (void*)(&Vs[bufn][slot * 8]));
      }
    }
  };

  // Q B-fragments (col = q = l31, k-window ks*16 + hl*8) for both q-groups.
  const int qrow0 = qt * 256 + w * 64;
  short8 bq[2][4];
#pragma unroll
  for (int qg = 0; qg < 2; qg++)
#pragma unroll
    for (int ks = 0; ks < 4; ks++)
      bq[qg][ks] = *(const short8*)(qp +
                                    (size_t)(qrow0 + qg * 32 + l31) * 64 +
                                    ks * 16 + hl * 8);

  f32x16 z16;
#pragma unroll
  for (int r = 0; r < 16; r++) z16[r] = 0.0f;
  f32x16 co[2][2] = {{z16, z16}, {z16, z16}};  // [qg][dt]
  float mrun[2] = {-INFINITY, -INFINITY};
  float lrun[2] = {0.0f, 0.0f};

  stage(0, 0);
  __syncthreads();

  for (int kt = 0; kt < 32; kt++) {
    const int cur = kt & 1;
    if (kt < 31) stage(cur ^ 1, (kt + 1) * 64);

    // ---- K fragments ONCE (8x ds_read_b128), shared by both q-groups.
    short8 kf[2][4];
#pragma unroll
    for (int g = 0; g < 2; g++)
#pragma unroll
      for (int ks = 0; ks < 4; ks++) {
        const int slot = (g * 32 + l31) * 8 + ((2 * ks + hl) ^ x7);
        kf[g][ks] = *(const short8*)(&Ks[cur][slot * 8]);
      }

    // ---- S^T: 16x mfma_32x32x16_bf16; ks=0 takes z16 as C-in (no zeroing).
    f32x16 sacc[2][2];  // [qg][g]
    __builtin_amdgcn_s_setprio(1);
#pragma unroll
    for (int qg = 0; qg < 2; qg++)
#pragma unroll
      for (int g = 0; g < 2; g++) {
        sacc[qg][g] = __builtin_amdgcn_mfma_f32_32x32x16_bf16(
            kf[g][0], bq[qg][0], z16, 0, 0, 0);
#pragma unroll
        for (int ks = 1; ks < 4; ks++)
          sacc[qg][g] = __builtin_amdgcn_mfma_f32_32x32x16_bf16(
              kf[g][ks], bq[qg][ks], sacc[qg][g], 0, 0, 0);
      }
    __builtin_amdgcn_s_setprio(0);

    // ---- V A-fragments ONCE (8x ds_read_b128), shared by both q-groups.
    half8 vf[2][2][2];  // [dt][g][s]
#pragma unroll
    for (int dt = 0; dt < 2; dt++)
#pragma unroll
      for (int g = 0; g < 2; g++)
#pragma unroll
        for (int s = 0; s < 2; s++) {
          const int slot = (dt * 32 + l31) * 8 + ((4 * g + 2 * s + hl) ^ x7);
          vf[dt][g][s] = *(const half8*)(&Vs[cur][slot * 8]);
        }

    // ---- per q-group: softmax + P pack/write/read + PV
#pragma unroll
    for (int qg = 0; qg < 2; qg++) {
      float pmax;
      {
        float tm[8];
#pragma unroll
        for (int r = 0; r < 8; r++)
          tm[r] = fmaxf(max3f(sacc[qg][0][r], sacc[qg][0][r + 8],
                              sacc[qg][1][r]),
                        sacc[qg][1][r + 8]);
        const float a0 = max3f(tm[0], tm[1], tm[2]);
        const float a1 = max3f(tm[3], tm[4], tm[5]);
        const float a2 = fmaxf(tm[6], tm[7]);
        pmax = max3f(a0, a1, a2);
      }
      pmax = fmaxf(pmax, __shfl_xor(pmax, 32, 64));
      if (!__all(pmax - mrun[qg] <= 8.0f)) {  // defer-max
        const float mnew = fmaxf(mrun[qg], pmax);
        const float a = fexp2(mrun[qg] - mnew);
        mrun[qg] = mnew;
        lrun[qg] *= a;
#pragma unroll
        for (int r = 0; r < 16; r++) {
          co[qg][0][r] *= a;
          co[qg][1][r] *= a;
        }
      }
      float ls0 = 0.0f, ls1 = 0.0f, ls2 = 0.0f, ls3 = 0.0f;
#pragma unroll
      for (int g = 0; g < 2; g++) {
#pragma unroll
        for (int r = 0; r < 16; r += 4) {
          const float p0 = fexp2(sacc[qg][g][r + 0] - mrun[qg]);
          const float p1 = fexp2(sacc[qg][g][r + 1] - mrun[qg]);
          const float p2 = fexp2(sacc[qg][g][r + 2] - mrun[qg]);
          const float p3 = fexp2(sacc[qg][g][r + 3] - mrun[qg]);
          sacc[qg][g][r + 0] = p0;
          sacc[qg][g][r + 1] = p1;
          sacc[qg][g][r + 2] = p2;
          sacc[qg][g][r + 3] = p3;
          ls0 += p0;
          ls1 += p1;
          ls2 += p2;
          ls3 += p3;
        }
      }
      lrun[qg] += (ls0 + ls1) + (ls2 + ls3);

      // P -> per-wave LDS tile at true key index (C-layout key_in_grp =
      // 8rg+4hl+t), then B-fragments with the V A-fragment convention;
      // g's MFMAs overlap g+1's pack. Pl reused across qg (in-order LDS).
#pragma unroll
      for (int g = 0; g < 2; g++) {
#pragma unroll
        for (int rg = 0; rg < 4; rg++) {
          u32x2 pw;
          pw[0] = pkrtz(sacc[qg][g][4 * rg + 0], sacc[qg][g][4 * rg + 1]);
          pw[1] = pkrtz(sacc[qg][g][4 * rg + 2], sacc[qg][g][4 * rg + 3]);
          *(u32x2*)(Pl + l31 * 64 + (((4 * g + rg) ^ x7) * 8) + hl * 4) = pw;
        }
        half8 pf[2];
#pragma unroll
        for (int s = 0; s < 2; s++)
          pf[s] =
              *(const half8*)(Pl + l31 * 64 + (((4 * g + 2 * s + hl) ^ x7) * 8));
        __builtin_amdgcn_s_setprio(1);
#pragma unroll
        for (int dt = 0; dt < 2; dt++)
#pragma unroll
          for (int s = 0; s < 2; s++)
            co[qg][dt] = __builtin_amdgcn_mfma_f32_32x32x16_f16(
                vf[dt][g][s], pf[s], co[qg][dt], 0, 0, 0);
        __builtin_amdgcn_s_setprio(0);
      }
    }
    __syncthreads();  // drains stage loads; separates buffer reuse
  }

  // ---- epilogue: normalize, transpose via LDS, coalesced b128 stores.
  unsigned short* Cw = smem + w * 4608;  // per-wave 64 rows x stride 72
#pragma unroll
  for (int qg = 0; qg < 2; qg++) {
    const float l = lrun[qg] + __shfl_xor(lrun[qg], 32, 64);
    const float inv = 1.0f / l;
#pragma unroll
    for (int dt = 0; dt < 2; dt++) {
#pragma unroll
      for (int r = 0; r < 16; r++) {
        const int d = dt * 32 + (r & 3) + 8 * (r >> 2) + 4 * hl;
        Cw[(qg * 32 + l31) * 72 + d] = bf16rne(co[qg][dt][r] * inv);
      }
    }
  }
  __syncthreads();
#pragma unroll
  for (int it = 0; it < 8; it++) {
    const int q = it * 8 + (lane >> 3);
    const int seg = lane & 7;
    const u32x4 o = *(const u32x4*)(Cw + q * 72 + seg * 8);
    *(u32x4*)(ctxr + (size_t)(b * 2048 + qrow0 + q) * 1024 + h * 64 + seg * 8) = o;
  }
}

// ---------------------------------------------------------------------------
extern "C" void kernel_launch(void* const* d_in, const int* in_sizes, int n_in,
                              void* d_out, int out_size, void* d_ws, size_t ws_size,
                              hipStream_t stream) {
  const float* Q = (const float*)d_in[0];
  const float* K = (const float*)d_in[1];
  const float* V = (const float*)d_in[2];
  const float* WQ = (const float*)d_in[3];
  const float* WK = (const float*)d_in[4];
  const float* WV = (const float*)d_in[5];
  const float* Wfc = (const float*)d_in[6];
  float* out = (float*)d_out;

  unsigned short* ws = (unsigned short*)d_ws;
  // ws layout (ushort units):
  //   Xb   @ 0         : 3*8388608  (bf16 Q,K,V)      [dead after projections]
  //   ctxr @ 0         : 8388608    (bf16 ctx)        [overlays Xb]
  //   Vt   @ 8388608   : 8388608    (f16 V^T)         [overlays Xb]
  //   Wt   @ 25165824  : 4*1048576  (bf16 W^T: q,k,v,fc)
  //   lin  @ 29360128  : 3*8388608  (bf16 projections)
  unsigned short* Xb = ws;
  unsigned short* ctxr = ws;
  unsigned short* Vt = ws + 8388608;
  unsigned short* Wt = ws + 25165824;
  unsigned short* lin = ws + 29360128;

  convert_x_kernel<<<dim3(4096, 3), 256, 0, stream>>>(Q, K, V, Xb);
  convert_w_kernel<<<dim3(32, 32, 4), 256, 0, stream>>>(WQ, WK, WV, Wfc, Wt);
  const float qscale = 0.125f * 1.4426950408889634f;  // 1/sqrt(dk) * log2(e)
  gemm_bt_kernel<<<dim3(32, 8, 3), 512, 0, stream>>>(Xb, Wt, lin, nullptr, qscale);
  vtrans_kernel<<<dim3(16, 64), 256, 0, stream>>>(lin + 16777216, Vt);
  attn_kernel<<<dim3(64, 8), 256, 0, stream>>>(lin, (const _Float16*)Vt, ctxr);
  gemm_bt_kernel<<<dim3(32, 8, 1), 512, 0, stream>>>(ctxr, Wt + 3 * 1048576, nullptr,
                                                     out, 1.0f);
}